// Round 9
// baseline (749.415 us; speedup 1.0000x reference)
//
#include <hip/hip_runtime.h>

#define CC 128
#define HH 128
#define WW 128
#define DH 64
#define DW 64
#define LTOT 4096          // DH*DW patches / fg positions
#define K0S 384            // 3*128 split-concat K for the pixel-pair GEMM
#define K2 2048            // CC*4*4
#define SCALE_F 10.0f
#define IMG ((size_t)CC * HH * WW)

typedef __attribute__((ext_vector_type(8))) short short8;
typedef __attribute__((ext_vector_type(4))) float f32x4;

// ---- pointer-pack structs (batch-merged prep via blockIdx.z) ----
struct Prep4 { const float* src[4]; unsigned short* dst[4]; int lo[4]; };
struct PtrS2 { const float* b[2]; float* ssq[2]; };
struct PtrN2 { const float* ssq[2]; float* invn[2]; float* mmv[2]; };
struct PtrR2 { const float* src[2]; unsigned short* dst[2]; };
struct PtrK2 { float* C[2]; };   // split-K partial outputs

// ---- bf16 helpers (RNE) ----
__device__ __forceinline__ unsigned short f2bf(float x) {
    union { float f; unsigned u; } v; v.f = x;
    unsigned r = v.u + 0x7fffu + ((v.u >> 16) & 1u);
    return (unsigned short)(r >> 16);
}
__device__ __forceinline__ float bf2f(unsigned short b) {
    union { unsigned u; float f; } v; v.u = ((unsigned)b) << 16;
    return v.f;
}

#define GLDS16(g, l) __builtin_amdgcn_global_load_lds( \
    (const __attribute__((address_space(1))) void*)(g), \
    (__attribute__((address_space(3))) void*)(l), 16, 0, 0)

// ---------------- downsample (::2) + fp32->bf16 split, row n = pixel, 384 = 3 segs * 128 ch ----
// b gets [hi, lo, hi], f gets [hi, hi, lo]  =>  products sum to hi*hi + lo*hi + hi*lo
__global__ __launch_bounds__(128) void split_ds_kernel(Prep4 P) {
    int z = blockIdx.z;
    const float* __restrict__ src = P.src[z];
    unsigned short* __restrict__ dst = P.dst[z];
    int lo_in_seg1 = P.lo[z];
    int n = blockIdx.x;          // 4096 pixels
    int c = threadIdx.x;         // 128 channels
    int ny = n >> 6, nx = n & 63;
    float v = src[((size_t)c * HH + 2 * ny) * WW + 2 * nx];
    unsigned short hi = f2bf(v);
    unsigned short lo = f2bf(v - bf2f(hi));
    unsigned short* drow = dst + (size_t)n * K0S;
    drow[c]       = hi;
    drow[128 + c] = lo_in_seg1 ? lo : hi;
    drow[256 + c] = lo_in_seg1 ? hi : lo;
}

// ---------------- raw 4x4 stride-2 patches of full-res b, transposed: dst[m2][p] bf16 ----------------
__global__ __launch_bounds__(256) void im2col_rawt_kernel(PtrR2 P) {
    int z = blockIdx.z;
    const float* __restrict__ src = P.src[z];
    unsigned short* __restrict__ dst = P.dst[z];
    int idx = blockIdx.x * 256 + threadIdx.x;   // K2*LTOT threads, p fastest
    int p = idx & (LTOT - 1);
    int m = idx >> 12;
    int px = p & 63, py = p >> 6;
    int ke = m & 3, kd = (m >> 2) & 3, c = m >> 4;
    int yy = 2 * py - 1 + kd, xx = 2 * px - 1 + ke;
    float v = 0.f;
    if (yy >= 0 && yy < HH && xx >= 0 && xx < WW)
        v = src[((size_t)c * HH + yy) * WW + xx];
    dst[idx] = f2bf(v);
}

// ---------------- per-pixel sum of squares over channels (on downsampled b) ----------------
__global__ void ssq_kernel(PtrS2 P) {
    int z = blockIdx.z;
    const float* __restrict__ b = P.b[z];
    float* __restrict__ ssq = P.ssq[z];
    int p = blockIdx.x * blockDim.x + threadIdx.x;     // 4096
    int px = p & 63, py = p >> 6;
    float s = 0.f;
    for (int c = 0; c < CC; ++c) {
        float v = b[((size_t)c * HH + 2 * py) * WW + 2 * px];
        s += v * v;
    }
    ssq[p] = s;
}

// ---------------- patch inverse norm + mask gate ----------------
__global__ void norm_mm_kernel(PtrN2 P, const float* __restrict__ mask) {
    int z = blockIdx.z;
    const float* __restrict__ ssq = P.ssq[z];
    float* __restrict__ inv_norm = P.invn[z];
    float* __restrict__ mmv = P.mmv[z];
    int p = blockIdx.x * blockDim.x + threadIdx.x;     // 4096
    int px = p & 63, py = p >> 6;
    float s = 0.f, ms = 0.f;
    for (int di = -1; di <= 1; ++di)
        for (int dj = -1; dj <= 1; ++dj) {
            int y = py + di, x = px + dj;
            if (y >= 0 && y < DH && x >= 0 && x < DW) {
                s += ssq[y * 64 + x];
                ms += mask[(size_t)(2 * y) * WW + 2 * x];
            }
        }
    float n = sqrtf(s);
    if (n < 1e-4f) n = 1e-4f;
    inv_norm[p] = 1.f / n;
    mmv[p] = (ms == 0.f) ? 1.f : 0.f;
}

// ---------------- bf16 MFMA GEMM (m97 structure + XOR bank swizzle) ----------------
// A[M][K], B[N][K], C[M][N] fp32. 128x128 tile, BK=32, 4 waves 2x2, 4x4 MFMA 16x16x32.
// LDS slot s (16B chunks) of row m holds global k-chunk s ^ ((m>>1)&3).
__global__ __launch_bounds__(256) void gemm_mfma(
    const unsigned short* __restrict__ Aop, const unsigned short* __restrict__ Bop,
    float* __restrict__ C, int M, int N, int K)
{
    __shared__ short As[128 * 32];
    __shared__ short Bs[128 * 32];
    int tid = threadIdx.x;
    int wave = tid >> 6, lane = tid & 63;
    int wm = (wave >> 1) * 64;
    int wn = (wave & 1) * 64;
    int bm = blockIdx.y * 128, bn = blockIdx.x * 128;

    int rowS = wave * 32;
    int lrow = lane >> 2;
    int lcol = (((lane & 3) ^ ((lrow >> 1) & 3)) * 8);

    f32x4 acc[4][4] = {};

    int quad = lane >> 4;
    int r16 = lane & 15;
    int slotA = (quad ^ ((r16 >> 1) & 3)) * 8;

    for (int k0 = 0; k0 < K; k0 += 32) {
        const unsigned short* ag = Aop + (size_t)(bm + rowS + lrow) * K + k0 + lcol;
        const unsigned short* bg = Bop + (size_t)(bn + rowS + lrow) * K + k0 + lcol;
        GLDS16(ag,                  As + rowS * 32);
        GLDS16(ag + 16 * (size_t)K, As + (rowS + 16) * 32);
        GLDS16(bg,                  Bs + rowS * 32);
        GLDS16(bg + 16 * (size_t)K, Bs + (rowS + 16) * 32);
        __syncthreads();

        short8 a[4], b[4];
#pragma unroll
        for (int i = 0; i < 4; ++i) {
            a[i] = *(const short8*)&As[(wm + i * 16 + r16) * 32 + slotA];
            b[i] = *(const short8*)&Bs[(wn + i * 16 + r16) * 32 + slotA];
        }
#pragma unroll
        for (int i = 0; i < 4; ++i)
#pragma unroll
            for (int j = 0; j < 4; ++j)
                acc[i][j] = __builtin_amdgcn_mfma_f32_16x16x32_bf16(a[i], b[j], acc[i][j], 0, 0, 0);
        __syncthreads();
    }

    int col = lane & 15, rq = (lane >> 4) * 4;
#pragma unroll
    for (int i = 0; i < 4; ++i) {
#pragma unroll
        for (int r = 0; r < 4; ++r) {
            int m = bm + wm + i * 16 + rq + r;
#pragma unroll
            for (int j = 0; j < 4; ++j)
                C[(size_t)m * N + bn + wn + j * 16 + col] = acc[i][j][r];
        }
    }
}

// ---------------- same GEMM, split-K over blockIdx.z (2 halves -> 2 partial C buffers) ----------------
__global__ __launch_bounds__(256) void gemm_splitk(
    const unsigned short* __restrict__ Aop, const unsigned short* __restrict__ Bop,
    PtrK2 G, int M, int N, int K)
{
    __shared__ short As[128 * 32];
    __shared__ short Bs[128 * 32];
    int z = blockIdx.z;
    float* __restrict__ C = G.C[z];
    int kbase = z * (K >> 1), kend = kbase + (K >> 1);
    int tid = threadIdx.x;
    int wave = tid >> 6, lane = tid & 63;
    int wm = (wave >> 1) * 64;
    int wn = (wave & 1) * 64;
    int bm = blockIdx.y * 128, bn = blockIdx.x * 128;

    int rowS = wave * 32;
    int lrow = lane >> 2;
    int lcol = (((lane & 3) ^ ((lrow >> 1) & 3)) * 8);

    f32x4 acc[4][4] = {};

    int quad = lane >> 4;
    int r16 = lane & 15;
    int slotA = (quad ^ ((r16 >> 1) & 3)) * 8;

    for (int k0 = kbase; k0 < kend; k0 += 32) {
        const unsigned short* ag = Aop + (size_t)(bm + rowS + lrow) * K + k0 + lcol;
        const unsigned short* bg = Bop + (size_t)(bn + rowS + lrow) * K + k0 + lcol;
        GLDS16(ag,                  As + rowS * 32);
        GLDS16(ag + 16 * (size_t)K, As + (rowS + 16) * 32);
        GLDS16(bg,                  Bs + rowS * 32);
        GLDS16(bg + 16 * (size_t)K, Bs + (rowS + 16) * 32);
        __syncthreads();

        short8 a[4], b[4];
#pragma unroll
        for (int i = 0; i < 4; ++i) {
            a[i] = *(const short8*)&As[(wm + i * 16 + r16) * 32 + slotA];
            b[i] = *(const short8*)&Bs[(wn + i * 16 + r16) * 32 + slotA];
        }
#pragma unroll
        for (int i = 0; i < 4; ++i)
#pragma unroll
            for (int j = 0; j < 4; ++j)
                acc[i][j] = __builtin_amdgcn_mfma_f32_16x16x32_bf16(a[i], b[j], acc[i][j], 0, 0, 0);
        __syncthreads();
    }

    int col = lane & 15, rq = (lane >> 4) * 4;
#pragma unroll
    for (int i = 0; i < 4; ++i) {
#pragma unroll
        for (int r = 0; r < 4; ++r) {
            int m = bm + wm + i * 16 + rq + r;
#pragma unroll
            for (int j = 0; j < 4; ++j)
                C[(size_t)m * N + bn + wn + j * 16 + col] = acc[i][j][r];
        }
    }
}

// ---------------- 9-tap patch stencil: S[q][p] = invn[p] * sum_{u,v} C[q+δ][p+δ], δ=64du+dv ----------------
// XCD swizzle: blocks with equal (blk&7) share an XCD and own a contiguous 512-row q range.
__global__ __launch_bounds__(256) void stencil_norm_kernel(
    const float* __restrict__ C, const float* __restrict__ invn,
    float* __restrict__ Sout)
{
    int blk = blockIdx.x;
    int q = ((blk & 7) << 9) | (blk >> 3);
    int t = threadIdx.x;
    int qy = q >> 6, qx = q & 63;
    int px = t & 63;
    int py0 = t >> 6;
    float acc[16] = {};
#pragma unroll
    for (int du = -1; du <= 1; ++du) {
        if (qy + du < 0 || qy + du > 63) continue;
#pragma unroll
        for (int dv = -1; dv <= 1; ++dv) {
            if (qx + dv < 0 || qx + dv > 63) continue;
            if (px + dv < 0 || px + dv > 63) continue;
            const float* row = C + (size_t)(q + 64 * du + dv) * LTOT + 64 * du + dv;
#pragma unroll
            for (int i = 0; i < 16; ++i) {
                int py = py0 + 4 * i;
                if (py + du < 0 || py + du > 63) continue;
                acc[i] += row[t + 256 * i];
            }
        }
    }
    float* orow = Sout + (size_t)q * LTOT;
#pragma unroll
    for (int i = 0; i < 16; ++i)
        orow[t + 256 * i] = acc[i] * invn[t + 256 * i];
}

// ---------------- fused: (fuse2 o fuse1) 9-tap diagonal stencil + row softmax + bf16 write ----------------
__global__ __launch_bounds__(256) void fused_conv_softmax_kernel(
    const float* __restrict__ S, const float* __restrict__ mmv,
    unsigned short* __restrict__ S16)
{
    __shared__ float redmax[4];
    __shared__ float redsum[4];
    int blk = blockIdx.x;
    int q = ((blk & 7) << 9) | (blk >> 3);
    int t = threadIdx.x;
    int lane = t & 63, wid = t >> 6;

    int rbase = ((q & 63) << 6) | (q >> 6);     // swap(q)
    int rrs[3];
    bool rok[3];
#pragma unroll
    for (int j = 0; j < 3; ++j) {
        int r2 = rbase + (j - 1);
        rok[j] = (r2 >= 0) && (r2 < LTOT);
        rrs[j] = ((r2 & 63) << 6) | ((r2 >> 6) & 63);   // swap(r2)
    }

    float v[16], m[16];
#pragma unroll
    for (int i = 0; i < 16; ++i) {
        int c = t + (i << 8);                   // column p, 0..4095
        int cbase = ((c & 63) << 6) | (c >> 6); // swap(c)
        float s = 0.f;
#pragma unroll
        for (int j = 0; j < 3; ++j) {           // d2 = j-1 (fuse2 order)
            if (!rok[j]) continue;
            int c2 = cbase + (j - 1);
            if (c2 < 0 || c2 >= LTOT) continue;
            int cc = ((c2 & 63) << 6) | (c2 >> 6);  // swap(c2); interior: c + 64*d2
            int rr = rrs[j];
            float tsum = 0.f;
#pragma unroll
            for (int d1 = -1; d1 <= 1; ++d1) {  // fuse1 order
                int a = rr + d1, bcol = cc + d1;
                if (a >= 0 && a < LTOT && bcol >= 0 && bcol < LTOT)
                    tsum += S[(size_t)a * LTOT + bcol];
            }
            s += tsum;
        }
        float mmx = mmv[c];
        m[i] = mmx;
        v[i] = s * mmx * SCALE_F;
    }

    float mx = v[0];
#pragma unroll
    for (int i = 1; i < 16; ++i) mx = fmaxf(mx, v[i]);
#pragma unroll
    for (int o = 32; o; o >>= 1) mx = fmaxf(mx, __shfl_xor(mx, o));
    if (lane == 0) redmax[wid] = mx;
    __syncthreads();
    float gmx = fmaxf(fmaxf(redmax[0], redmax[1]), fmaxf(redmax[2], redmax[3]));

    float s = 0.f;
#pragma unroll
    for (int i = 0; i < 16; ++i) {
        v[i] = __expf(v[i] - gmx);
        s += v[i];
    }
#pragma unroll
    for (int o = 32; o; o >>= 1) s += __shfl_xor(s, o);
    if (lane == 0) redsum[wid] = s;
    __syncthreads();
    float inv = 1.f / (redsum[0] + redsum[1] + redsum[2] + redsum[3]);

    unsigned short* orow = S16 + (size_t)q * LTOT;
#pragma unroll
    for (int i = 0; i < 16; ++i)
        orow[t + (i << 8)] = f2bf(v[i] * inv * m[i]);
}

// ---------------- overlap-add of weighted 4x4 patches (stride 2), /4; sums split-K partials ----------------
__global__ void output_kernel(const float* __restrict__ P0, const float* __restrict__ P1,
                              float* __restrict__ out) {
    int idx = blockIdx.x * blockDim.x + threadIdx.x;   // CC*HH*WW
    int x = idx & 127;
    int y = (idx >> 7) & 127;
    int c = idx >> 14;
    int oylo = max(0, (y - 1) >> 1), oyhi = min(63, (y + 1) >> 1);
    int oxlo = max(0, (x - 1) >> 1), oxhi = min(63, (x + 1) >> 1);
    float s = 0.f;
    for (int oy = oylo; oy <= oyhi; ++oy)
        for (int ox = oxlo; ox <= oxhi; ++ox) {
            int kd = y - 2 * oy + 1;
            int ke = x - 2 * ox + 1;
            size_t o = (size_t)(oy * 64 + ox) * K2 + c * 16 + kd * 4 + ke;
            s += P0[o] + P1[o];
        }
    out[idx] = s * 0.25f;
}

extern "C" void kernel_launch(void* const* d_in, const int* in_sizes, int n_in,
                              void* d_out, int out_size, void* d_ws, size_t ws_size,
                              hipStream_t stream) {
    (void)in_sizes; (void)n_in; (void)out_size; (void)ws_size;
    const float* f    = (const float*)d_in[0];
    const float* b    = (const float*)d_in[1];
    const float* mask = (const float*)d_in[2];
    float* out = (float*)d_out;

    const size_t SZ_MAT  = (size_t)LTOT * LTOT * 4;   // 64 MB
    const size_t SZ_WR   = (size_t)K2 * LTOT * 2;     // 16 MB
    const size_t SZ_SP   = (size_t)LTOT * K0S * 2;    // 3 MB
    const size_t SZ_V    = (size_t)LTOT * 4;

    auto pad = [](size_t n) { return (n + 255) & ~(size_t)255; };
    char* p = (char*)d_ws;
    auto take = [&](size_t n) -> void* { void* r = (void*)p; p += pad(n); return r; };

    // total footprint: 64 + 64 + 16 + 16 + 4*3 + 6*16K ~= 172 MB (< proven-safe 185 MB)
    float* Buf1 = (float*)take(SZ_MAT);   // Cpix -> [S16 (32MB) | part0 (32MB)]
    float* Buf2 = (float*)take(SZ_MAT);   // Sp   -> [part1 (32MB) | free]
    unsigned short* W0 = (unsigned short*)take(SZ_WR);
    unsigned short* W1 = (unsigned short*)take(SZ_WR);
    unsigned short* Bsp0 = (unsigned short*)take(SZ_SP);
    unsigned short* Fsp0 = (unsigned short*)take(SZ_SP);
    unsigned short* Bsp1 = (unsigned short*)take(SZ_SP);
    unsigned short* Fsp1 = (unsigned short*)take(SZ_SP);
    float* ssq0 = (float*)take(SZ_V);  float* ssq1 = (float*)take(SZ_V);
    float* invn0 = (float*)take(SZ_V); float* invn1 = (float*)take(SZ_V);
    float* mmv0 = (float*)take(SZ_V);  float* mmv1 = (float*)take(SZ_V);

    const float* f0 = f,  *b0 = b;
    const float* f1 = f + IMG, *b1 = b + IMG;

    unsigned short* S16  = (unsigned short*)Buf1;                  // 32 MB
    float* part0 = (float*)((char*)Buf1 + SZ_MAT / 2);             // 32 MB
    float* part1 = Buf2;                                           // 32 MB (Sp dead)

    // ---- merged prep (both batches) ----
    Prep4 P{{b0, f0, b1, f1}, {Bsp0, Fsp0, Bsp1, Fsp1}, {1, 0, 1, 0}};
    split_ds_kernel<<<dim3(LTOT, 1, 4), 128, 0, stream>>>(P);
    PtrS2 sq{{b0, b1}, {ssq0, ssq1}};
    ssq_kernel<<<dim3(16, 1, 2), 256, 0, stream>>>(sq);
    PtrN2 nm{{ssq0, ssq1}, {invn0, invn1}, {mmv0, mmv1}};
    norm_mm_kernel<<<dim3(16, 1, 2), 256, 0, stream>>>(nm, mask);
    PtrR2 rw{{b0, b1}, {W0, W1}};
    im2col_rawt_kernel<<<dim3((size_t)K2 * LTOT / 256, 1, 2), 256, 0, stream>>>(rw);

    // ---- per-batch pipeline ----
    for (int bi = 0; bi < 2; ++bi) {
        const unsigned short* Fsp = bi ? Fsp1 : Fsp0;
        const unsigned short* Bsp = bi ? Bsp1 : Bsp0;
        const unsigned short* W   = bi ? W1 : W0;
        const float* invn = bi ? invn1 : invn0;
        const float* mmv  = bi ? mmv1 : mmv0;

        // Cpix[q][p] = sum_c fd[c][q]*bd[c][p]   (split-concat fp32-accurate, K=384)
        gemm_mfma<<<dim3(32, 32), 256, 0, stream>>>(Fsp, Bsp, Buf1, LTOT, LTOT, K0S);

        // patch inner products: 9-tap diagonal stencil + invn column scale
        stencil_norm_kernel<<<LTOT, 256, 0, stream>>>(Buf1, invn, Buf2);

        // fused (fuse2 o fuse1) + softmax + bf16 cast  (Cpix dead -> S16 in Buf1 lower half)
        fused_conv_softmax_kernel<<<LTOT, 256, 0, stream>>>(Buf2, mmv, S16);

        // split-K GEMM2 (1024 blocks): part_z[q][m2] = sum_{p in half z} S16[q][p] * W[m2][p]
        PtrK2 g2{{part0, part1}};
        gemm_splitk<<<dim3(K2 / 128, LTOT / 128, 2), 256, 0, stream>>>(
            S16, W, g2, LTOT, K2, LTOT);

        output_kernel<<<CC * HH * WW / 256, 256, 0, stream>>>(
            part0, part1, out + (size_t)bi * IMG);
    }
}

// Round 10
// 635.421 us; speedup vs baseline: 1.1794x; 1.1794x over previous
//
#include <hip/hip_runtime.h>

#define CC 128
#define HH 128
#define WW 128
#define DH 64
#define DW 64
#define LTOT 4096          // DH*DW patches / fg positions
#define K0S 384            // 3*128 split-concat K for the pixel-pair GEMM
#define K2 2048            // CC*4*4
#define SCALE_F 10.0f
#define IMG ((size_t)CC * HH * WW)

typedef __attribute__((ext_vector_type(8))) short short8;
typedef __attribute__((ext_vector_type(4))) float f32x4;

// ---- pointer-pack structs (batch-merged prep via blockIdx.z) ----
struct Prep4 { const float* src[4]; unsigned short* dst[4]; float* ssq[4]; int lo[4]; };
struct PtrN2 { const float* ssq[2]; float* invn[2]; float* mmv[2]; };
struct PtrR2 { const float* src[2]; unsigned short* dst[2]; };

// ---- bf16 helpers (RNE) ----
__device__ __forceinline__ unsigned short f2bf(float x) {
    union { float f; unsigned u; } v; v.f = x;
    unsigned r = v.u + 0x7fffu + ((v.u >> 16) & 1u);
    return (unsigned short)(r >> 16);
}
__device__ __forceinline__ float bf2f(unsigned short b) {
    union { unsigned u; float f; } v; v.u = ((unsigned)b) << 16;
    return v.f;
}

#define GLDS16(g, l) __builtin_amdgcn_global_load_lds( \
    (const __attribute__((address_space(1))) void*)(g), \
    (__attribute__((address_space(3))) void*)(l), 16, 0, 0)

// ---------------- downsample (::2) + fp32->bf16 split + (for b) fused ssq reduce ----------------
// b gets [hi, lo, hi], f gets [hi, hi, lo]  =>  products sum to hi*hi + lo*hi + hi*lo
__global__ __launch_bounds__(128) void split_ds_kernel(Prep4 P) {
    __shared__ float partial[2];
    int z = blockIdx.z;
    const float* __restrict__ src = P.src[z];
    unsigned short* __restrict__ dst = P.dst[z];
    int lo_in_seg1 = P.lo[z];
    int n = blockIdx.x;          // 4096 pixels
    int c = threadIdx.x;         // 128 channels
    int ny = n >> 6, nx = n & 63;
    float v = src[((size_t)c * HH + 2 * ny) * WW + 2 * nx];
    unsigned short hi = f2bf(v);
    unsigned short lo = f2bf(v - bf2f(hi));
    unsigned short* drow = dst + (size_t)n * K0S;
    drow[c]       = hi;
    drow[128 + c] = lo_in_seg1 ? lo : hi;
    drow[256 + c] = lo_in_seg1 ? hi : lo;

    float* ssq = P.ssq[z];
    if (ssq) {                   // b images only: per-pixel channel sum of squares
        float s2 = v * v;
#pragma unroll
        for (int o = 32; o; o >>= 1) s2 += __shfl_xor(s2, o);
        if ((threadIdx.x & 63) == 0) partial[threadIdx.x >> 6] = s2;
        __syncthreads();
        if (threadIdx.x == 0) ssq[n] = partial[0] + partial[1];
    }
}

// ---------------- raw 4x4 stride-2 patches of full-res b, transposed: dst[m2][p] bf16 ----------------
__global__ __launch_bounds__(256) void im2col_rawt_kernel(PtrR2 P) {
    int z = blockIdx.z;
    const float* __restrict__ src = P.src[z];
    unsigned short* __restrict__ dst = P.dst[z];
    int idx = blockIdx.x * 256 + threadIdx.x;   // K2*LTOT threads, p fastest
    int p = idx & (LTOT - 1);
    int m = idx >> 12;
    int px = p & 63, py = p >> 6;
    int ke = m & 3, kd = (m >> 2) & 3, c = m >> 4;
    int yy = 2 * py - 1 + kd, xx = 2 * px - 1 + ke;
    float v = 0.f;
    if (yy >= 0 && yy < HH && xx >= 0 && xx < WW)
        v = src[((size_t)c * HH + yy) * WW + xx];
    dst[idx] = f2bf(v);
}

// ---------------- patch inverse norm + mask gate ----------------
__global__ void norm_mm_kernel(PtrN2 P, const float* __restrict__ mask) {
    int z = blockIdx.z;
    const float* __restrict__ ssq = P.ssq[z];
    float* __restrict__ inv_norm = P.invn[z];
    float* __restrict__ mmv = P.mmv[z];
    int p = blockIdx.x * blockDim.x + threadIdx.x;     // 4096
    int px = p & 63, py = p >> 6;
    float s = 0.f, ms = 0.f;
    for (int di = -1; di <= 1; ++di)
        for (int dj = -1; dj <= 1; ++dj) {
            int y = py + di, x = px + dj;
            if (y >= 0 && y < DH && x >= 0 && x < DW) {
                s += ssq[y * 64 + x];
                ms += mask[(size_t)(2 * y) * WW + 2 * x];
            }
        }
    float n = sqrtf(s);
    if (n < 1e-4f) n = 1e-4f;
    inv_norm[p] = 1.f / n;
    mmv[p] = (ms == 0.f) ? 1.f : 0.f;
}

// ---------------- bf16 MFMA GEMM, BK=64 (m97 structure, 2x MFMA per barrier, XOR swizzle) ------
// A[M][K], B[N][K], C[M][N] fp32. 128x128 tile, BK=64, 4 waves 2x2, each 4x4x(2 k-slab) MFMA.
// LDS rows of 128B = 8 chunks of 16B; chunk slot s of row m holds global chunk s ^ (m&7).
// Per-acc K order identical to BK=32 version (slab0 then slab1) -> bit-identical results.
__global__ __launch_bounds__(256) void gemm_mfma(
    const unsigned short* __restrict__ Aop, const unsigned short* __restrict__ Bop,
    float* __restrict__ C, int M, int N, int K)
{
    __shared__ short As[128 * 64];
    __shared__ short Bs[128 * 64];
    int tid = threadIdx.x;
    int wave = tid >> 6, lane = tid & 63;
    int wm = (wave >> 1) * 64;
    int wn = (wave & 1) * 64;
    int bm = blockIdx.y * 128, bn = blockIdx.x * 128;

    int rowS = wave * 32;              // wave stages rows [rowS, rowS+32)
    int lrow8 = lane >> 3;             // 0..7 (row within 8-row staging group)
    int gchunk = ((lane & 7) ^ lrow8) * 8;   // swizzled global k-offset (shorts)

    f32x4 acc[4][4] = {};

    int quad = lane >> 4;              // 0..3
    int r16 = lane & 15;
    int pc0 = ((quad)     ^ (r16 & 7)) * 8;  // physical chunk of k-slab 0
    int pc1 = ((4 + quad) ^ (r16 & 7)) * 8;  // physical chunk of k-slab 1

    for (int k0 = 0; k0 < K; k0 += 64) {
#pragma unroll
        for (int it = 0; it < 4; ++it) {
            int r = rowS + it * 8;     // wave-uniform LDS base; lanes scatter +lane*16B
            GLDS16(Aop + (size_t)(bm + r + lrow8) * K + k0 + gchunk, As + r * 64);
            GLDS16(Bop + (size_t)(bn + r + lrow8) * K + k0 + gchunk, Bs + r * 64);
        }
        __syncthreads();

        short8 a0[4], b0[4], a1[4], b1[4];
#pragma unroll
        for (int i = 0; i < 4; ++i) {
            a0[i] = *(const short8*)&As[(wm + i * 16 + r16) * 64 + pc0];
            b0[i] = *(const short8*)&Bs[(wn + i * 16 + r16) * 64 + pc0];
            a1[i] = *(const short8*)&As[(wm + i * 16 + r16) * 64 + pc1];
            b1[i] = *(const short8*)&Bs[(wn + i * 16 + r16) * 64 + pc1];
        }
#pragma unroll
        for (int i = 0; i < 4; ++i)
#pragma unroll
            for (int j = 0; j < 4; ++j) {
                acc[i][j] = __builtin_amdgcn_mfma_f32_16x16x32_bf16(a0[i], b0[j], acc[i][j], 0, 0, 0);
                acc[i][j] = __builtin_amdgcn_mfma_f32_16x16x32_bf16(a1[i], b1[j], acc[i][j], 0, 0, 0);
            }
        __syncthreads();
    }

    int col = lane & 15, rq = (lane >> 4) * 4;
#pragma unroll
    for (int i = 0; i < 4; ++i) {
#pragma unroll
        for (int r = 0; r < 4; ++r) {
            int m = bm + wm + i * 16 + rq + r;
#pragma unroll
            for (int j = 0; j < 4; ++j)
                C[(size_t)m * N + bn + wn + j * 16 + col] = acc[i][j][r];
        }
    }
}

// ---------------- 9-tap patch stencil: S[q][p] = invn[p] * sum_{u,v} C[q+δ][p+δ], δ=64du+dv ----------------
// XCD swizzle: blocks with equal (blk&7) share an XCD and own a contiguous 512-row q range.
__global__ __launch_bounds__(256) void stencil_norm_kernel(
    const float* __restrict__ C, const float* __restrict__ invn,
    float* __restrict__ Sout)
{
    int blk = blockIdx.x;
    int q = ((blk & 7) << 9) | (blk >> 3);
    int t = threadIdx.x;
    int qy = q >> 6, qx = q & 63;
    int px = t & 63;
    int py0 = t >> 6;
    float acc[16] = {};
#pragma unroll
    for (int du = -1; du <= 1; ++du) {
        if (qy + du < 0 || qy + du > 63) continue;
#pragma unroll
        for (int dv = -1; dv <= 1; ++dv) {
            if (qx + dv < 0 || qx + dv > 63) continue;
            if (px + dv < 0 || px + dv > 63) continue;
            const float* row = C + (size_t)(q + 64 * du + dv) * LTOT + 64 * du + dv;
#pragma unroll
            for (int i = 0; i < 16; ++i) {
                int py = py0 + 4 * i;
                if (py + du < 0 || py + du > 63) continue;
                acc[i] += row[t + 256 * i];
            }
        }
    }
    float* orow = Sout + (size_t)q * LTOT;
#pragma unroll
    for (int i = 0; i < 16; ++i)
        orow[t + 256 * i] = acc[i] * invn[t + 256 * i];
}

// ---------------- fused: (fuse2 o fuse1) 9-tap diagonal stencil + row softmax + bf16 write ----------------
__global__ __launch_bounds__(256) void fused_conv_softmax_kernel(
    const float* __restrict__ S, const float* __restrict__ mmv,
    unsigned short* __restrict__ S16)
{
    __shared__ float redmax[4];
    __shared__ float redsum[4];
    int blk = blockIdx.x;
    int q = ((blk & 7) << 9) | (blk >> 3);
    int t = threadIdx.x;
    int lane = t & 63, wid = t >> 6;

    int rbase = ((q & 63) << 6) | (q >> 6);     // swap(q)
    int rrs[3];
    bool rok[3];
#pragma unroll
    for (int j = 0; j < 3; ++j) {
        int r2 = rbase + (j - 1);
        rok[j] = (r2 >= 0) && (r2 < LTOT);
        rrs[j] = ((r2 & 63) << 6) | ((r2 >> 6) & 63);   // swap(r2)
    }

    float v[16], m[16];
#pragma unroll
    for (int i = 0; i < 16; ++i) {
        int c = t + (i << 8);                   // column p, 0..4095
        int cbase = ((c & 63) << 6) | (c >> 6); // swap(c)
        float s = 0.f;
#pragma unroll
        for (int j = 0; j < 3; ++j) {           // d2 = j-1 (fuse2 order)
            if (!rok[j]) continue;
            int c2 = cbase + (j - 1);
            if (c2 < 0 || c2 >= LTOT) continue;
            int cc = ((c2 & 63) << 6) | (c2 >> 6);  // swap(c2); interior: c + 64*d2
            int rr = rrs[j];
            float tsum = 0.f;
#pragma unroll
            for (int d1 = -1; d1 <= 1; ++d1) {  // fuse1 order
                int a = rr + d1, bcol = cc + d1;
                if (a >= 0 && a < LTOT && bcol >= 0 && bcol < LTOT)
                    tsum += S[(size_t)a * LTOT + bcol];
            }
            s += tsum;
        }
        float mmx = mmv[c];
        m[i] = mmx;
        v[i] = s * mmx * SCALE_F;
    }

    float mx = v[0];
#pragma unroll
    for (int i = 1; i < 16; ++i) mx = fmaxf(mx, v[i]);
#pragma unroll
    for (int o = 32; o; o >>= 1) mx = fmaxf(mx, __shfl_xor(mx, o));
    if (lane == 0) redmax[wid] = mx;
    __syncthreads();
    float gmx = fmaxf(fmaxf(redmax[0], redmax[1]), fmaxf(redmax[2], redmax[3]));

    float s = 0.f;
#pragma unroll
    for (int i = 0; i < 16; ++i) {
        v[i] = __expf(v[i] - gmx);
        s += v[i];
    }
#pragma unroll
    for (int o = 32; o; o >>= 1) s += __shfl_xor(s, o);
    if (lane == 0) redsum[wid] = s;
    __syncthreads();
    float inv = 1.f / (redsum[0] + redsum[1] + redsum[2] + redsum[3]);

    unsigned short* orow = S16 + (size_t)q * LTOT;
#pragma unroll
    for (int i = 0; i < 16; ++i)
        orow[t + (i << 8)] = f2bf(v[i] * inv * m[i]);
}

// ---------------- overlap-add of weighted 4x4 patches (stride 2), /4 ----------------
__global__ void output_kernel(const float* __restrict__ C2, float* __restrict__ out) {
    int idx = blockIdx.x * blockDim.x + threadIdx.x;   // CC*HH*WW
    int x = idx & 127;
    int y = (idx >> 7) & 127;
    int c = idx >> 14;
    int oylo = max(0, (y - 1) >> 1), oyhi = min(63, (y + 1) >> 1);
    int oxlo = max(0, (x - 1) >> 1), oxhi = min(63, (x + 1) >> 1);
    float s = 0.f;
    for (int oy = oylo; oy <= oyhi; ++oy)
        for (int ox = oxlo; ox <= oxhi; ++ox) {
            int kd = y - 2 * oy + 1;
            int ke = x - 2 * ox + 1;
            s += C2[(size_t)(oy * 64 + ox) * K2 + c * 16 + kd * 4 + ke];
        }
    out[idx] = s * 0.25f;
}

extern "C" void kernel_launch(void* const* d_in, const int* in_sizes, int n_in,
                              void* d_out, int out_size, void* d_ws, size_t ws_size,
                              hipStream_t stream) {
    (void)in_sizes; (void)n_in; (void)out_size; (void)ws_size;
    const float* f    = (const float*)d_in[0];
    const float* b    = (const float*)d_in[1];
    const float* mask = (const float*)d_in[2];
    float* out = (float*)d_out;

    const size_t SZ_MAT = (size_t)LTOT * LTOT * 4;   // 64 MB
    const size_t SZ_WR  = (size_t)K2 * LTOT * 2;     // 16 MB
    const size_t SZ_SP  = (size_t)LTOT * K0S * 2;    // 3 MB
    const size_t SZ_V   = (size_t)LTOT * 4;

    auto pad = [](size_t n) { return (n + 255) & ~(size_t)255; };
    char* p = (char*)d_ws;
    auto take = [&](size_t n) -> void* { void* r = (void*)p; p += pad(n); return r; };

    // footprint: 64 + 64 + 16 + 16 + 4*3 + small ~= 172 MB (proven-safe)
    float* Buf1 = (float*)take(SZ_MAT);   // Cpix -> S16 (lower 32 MB)
    float* Buf2 = (float*)take(SZ_MAT);   // Sp   -> C2 (lower 32 MB)
    unsigned short* W0 = (unsigned short*)take(SZ_WR);
    unsigned short* W1 = (unsigned short*)take(SZ_WR);
    unsigned short* Bsp0 = (unsigned short*)take(SZ_SP);
    unsigned short* Fsp0 = (unsigned short*)take(SZ_SP);
    unsigned short* Bsp1 = (unsigned short*)take(SZ_SP);
    unsigned short* Fsp1 = (unsigned short*)take(SZ_SP);
    float* ssq0 = (float*)take(SZ_V);  float* ssq1 = (float*)take(SZ_V);
    float* invn0 = (float*)take(SZ_V); float* invn1 = (float*)take(SZ_V);
    float* mmv0 = (float*)take(SZ_V);  float* mmv1 = (float*)take(SZ_V);

    const float* f0 = f,  *b0 = b;
    const float* f1 = f + IMG, *b1 = b + IMG;

    unsigned short* S16 = (unsigned short*)Buf1;   // 32 MB, after Cpix dead
    float* C2 = Buf2;                               // 32 MB, after Sp dead

    // ---- merged prep (both batches); ssq fused into the b split passes ----
    Prep4 P{{b0, f0, b1, f1}, {Bsp0, Fsp0, Bsp1, Fsp1},
            {ssq0, nullptr, ssq1, nullptr}, {1, 0, 1, 0}};
    split_ds_kernel<<<dim3(LTOT, 1, 4), 128, 0, stream>>>(P);
    PtrN2 nm{{ssq0, ssq1}, {invn0, invn1}, {mmv0, mmv1}};
    norm_mm_kernel<<<dim3(16, 1, 2), 256, 0, stream>>>(nm, mask);
    PtrR2 rw{{b0, b1}, {W0, W1}};
    im2col_rawt_kernel<<<dim3((size_t)K2 * LTOT / 256, 1, 2), 256, 0, stream>>>(rw);

    // ---- per-batch pipeline ----
    for (int bi = 0; bi < 2; ++bi) {
        const unsigned short* Fsp = bi ? Fsp1 : Fsp0;
        const unsigned short* Bsp = bi ? Bsp1 : Bsp0;
        const unsigned short* W   = bi ? W1 : W0;
        const float* invn = bi ? invn1 : invn0;
        const float* mmv  = bi ? mmv1 : mmv0;

        // Cpix[q][p] = sum_c fd[c][q]*bd[c][p]   (split-concat fp32-accurate, K=384)
        gemm_mfma<<<dim3(32, 32), 256, 0, stream>>>(Fsp, Bsp, Buf1, LTOT, LTOT, K0S);

        // patch inner products: 9-tap diagonal stencil + invn column scale
        stencil_norm_kernel<<<LTOT, 256, 0, stream>>>(Buf1, invn, Buf2);

        // fused (fuse2 o fuse1) + softmax + bf16 cast  (Cpix dead -> S16 in Buf1 lower half)
        fused_conv_softmax_kernel<<<LTOT, 256, 0, stream>>>(Buf2, mmv, S16);

        // C2[q][m2] = sum_p S16[q][p] * W[m2][p]   (Sp dead -> C2 in Buf2 lower half)
        gemm_mfma<<<dim3(K2 / 128, LTOT / 128), 256, 0, stream>>>(S16, W, C2, LTOT, K2, LTOT);

        output_kernel<<<CC * HH * WW / 256, 256, 0, stream>>>(C2, out + (size_t)bi * IMG);
    }
}

// Round 11
// 597.764 us; speedup vs baseline: 1.2537x; 1.0630x over previous
//
#include <hip/hip_runtime.h>

#define CC 128
#define HH 128
#define WW 128
#define DH 64
#define DW 64
#define LTOT 4096          // DH*DW patches / fg positions
#define K0S 384            // 3*128 split-concat K for the pixel-pair GEMM
#define K2 2048            // CC*4*4
#define SCALE_F 10.0f
#define IMG ((size_t)CC * HH * WW)

typedef __attribute__((ext_vector_type(8))) short short8;
typedef __attribute__((ext_vector_type(4))) float f32x4;

// ---- pointer-pack structs (batch-merged prep via blockIdx.z) ----
struct Prep4 { const float* src[4]; unsigned short* dst[4]; float* ssq[4]; int lo[4]; };
struct PtrN2 { const float* ssq[2]; float* invn[2]; float* mmv[2]; };
struct PtrR2 { const float* src[2]; unsigned short* dst[2]; };

// ---- bf16 helpers (RNE) ----
__device__ __forceinline__ unsigned short f2bf(float x) {
    union { float f; unsigned u; } v; v.f = x;
    unsigned r = v.u + 0x7fffu + ((v.u >> 16) & 1u);
    return (unsigned short)(r >> 16);
}
__device__ __forceinline__ float bf2f(unsigned short b) {
    union { unsigned u; float f; } v; v.u = ((unsigned)b) << 16;
    return v.f;
}

#define GLDS16(g, l) __builtin_amdgcn_global_load_lds( \
    (const __attribute__((address_space(1))) void*)(g), \
    (__attribute__((address_space(3))) void*)(l), 16, 0, 0)

// ---------------- downsample (::2) + fp32->bf16 split + (for b) fused ssq reduce ----------------
// b gets [hi, lo, hi], f gets [hi, hi, lo]  =>  products sum to hi*hi + lo*hi + hi*lo
__global__ __launch_bounds__(128) void split_ds_kernel(Prep4 P) {
    __shared__ float partial[2];
    int z = blockIdx.z;
    const float* __restrict__ src = P.src[z];
    unsigned short* __restrict__ dst = P.dst[z];
    int lo_in_seg1 = P.lo[z];
    int n = blockIdx.x;          // 4096 pixels
    int c = threadIdx.x;         // 128 channels
    int ny = n >> 6, nx = n & 63;
    float v = src[((size_t)c * HH + 2 * ny) * WW + 2 * nx];
    unsigned short hi = f2bf(v);
    unsigned short lo = f2bf(v - bf2f(hi));
    unsigned short* drow = dst + (size_t)n * K0S;
    drow[c]       = hi;
    drow[128 + c] = lo_in_seg1 ? lo : hi;
    drow[256 + c] = lo_in_seg1 ? hi : lo;

    float* ssq = P.ssq[z];
    if (ssq) {                   // b images only: per-pixel channel sum of squares
        float s2 = v * v;
#pragma unroll
        for (int o = 32; o; o >>= 1) s2 += __shfl_xor(s2, o);
        if ((threadIdx.x & 63) == 0) partial[threadIdx.x >> 6] = s2;
        __syncthreads();
        if (threadIdx.x == 0) ssq[n] = partial[0] + partial[1];
    }
}

// ---------------- raw 4x4 stride-2 patches of full-res b, transposed: dst[m2][p] bf16 ----------------
__global__ __launch_bounds__(256) void im2col_rawt_kernel(PtrR2 P) {
    int z = blockIdx.z;
    const float* __restrict__ src = P.src[z];
    unsigned short* __restrict__ dst = P.dst[z];
    int idx = blockIdx.x * 256 + threadIdx.x;   // K2*LTOT threads, p fastest
    int p = idx & (LTOT - 1);
    int m = idx >> 12;
    int px = p & 63, py = p >> 6;
    int ke = m & 3, kd = (m >> 2) & 3, c = m >> 4;
    int yy = 2 * py - 1 + kd, xx = 2 * px - 1 + ke;
    float v = 0.f;
    if (yy >= 0 && yy < HH && xx >= 0 && xx < WW)
        v = src[((size_t)c * HH + yy) * WW + xx];
    dst[idx] = f2bf(v);
}

// ---------------- patch inverse norm + mask gate ----------------
__global__ void norm_mm_kernel(PtrN2 P, const float* __restrict__ mask) {
    int z = blockIdx.z;
    const float* __restrict__ ssq = P.ssq[z];
    float* __restrict__ inv_norm = P.invn[z];
    float* __restrict__ mmv = P.mmv[z];
    int p = blockIdx.x * blockDim.x + threadIdx.x;     // 4096
    int px = p & 63, py = p >> 6;
    float s = 0.f, ms = 0.f;
    for (int di = -1; di <= 1; ++di)
        for (int dj = -1; dj <= 1; ++dj) {
            int y = py + di, x = px + dj;
            if (y >= 0 && y < DH && x >= 0 && x < DW) {
                s += ssq[y * 64 + x];
                ms += mask[(size_t)(2 * y) * WW + 2 * x];
            }
        }
    float n = sqrtf(s);
    if (n < 1e-4f) n = 1e-4f;
    inv_norm[p] = 1.f / n;
    mmv[p] = (ms == 0.f) ? 1.f : 0.f;
}

// ---------------- bf16 MFMA GEMM, BK=64, hoisted running pointers, XOR swizzle ----------------
// A[M][K], B[N][K], C[M][N] fp32. 128x128 tile, 4 waves 2x2, each 4x4x(2 k-slab) MFMA 16x16x32.
// LDS rows of 128B = 8 chunks of 16B; chunk slot s of row m holds global chunk s ^ (m&7).
// K-loop address math strength-reduced: 8 per-lane pointers advance by BK each iter
// (compiler does NOT do this itself: m97 disasm shows per-iter v_lshl_add_u64 chains).
__global__ __launch_bounds__(256) void gemm_mfma(
    const unsigned short* __restrict__ Aop, const unsigned short* __restrict__ Bop,
    float* __restrict__ C, int M, int N, int K)
{
    __shared__ short As[128 * 64];
    __shared__ short Bs[128 * 64];
    int tid = threadIdx.x;
    int wave = tid >> 6, lane = tid & 63;
    int wm = (wave >> 1) * 64;
    int wn = (wave & 1) * 64;
    int bm = blockIdx.y * 128, bn = blockIdx.x * 128;

    int rowS = wave * 32;              // wave stages rows [rowS, rowS+32)
    int lrow8 = lane >> 3;             // 0..7 (row within 8-row staging group)
    int gchunk = ((lane & 7) ^ lrow8) * 8;   // swizzled global k-offset (shorts)

    f32x4 acc[4][4] = {};

    int quad = lane >> 4;              // 0..3
    int r16 = lane & 15;
    int pc0 = ((quad)     ^ (r16 & 7)) * 8;  // physical chunk of k-slab 0
    int pc1 = ((4 + quad) ^ (r16 & 7)) * 8;  // physical chunk of k-slab 1

    // hoisted running pointers (k0-invariant base; += 64 shorts per iter)
    const unsigned short* ap0 = Aop + (size_t)(bm + rowS +  0 + lrow8) * K + gchunk;
    const unsigned short* ap1 = Aop + (size_t)(bm + rowS +  8 + lrow8) * K + gchunk;
    const unsigned short* ap2 = Aop + (size_t)(bm + rowS + 16 + lrow8) * K + gchunk;
    const unsigned short* ap3 = Aop + (size_t)(bm + rowS + 24 + lrow8) * K + gchunk;
    const unsigned short* bp0 = Bop + (size_t)(bn + rowS +  0 + lrow8) * K + gchunk;
    const unsigned short* bp1 = Bop + (size_t)(bn + rowS +  8 + lrow8) * K + gchunk;
    const unsigned short* bp2 = Bop + (size_t)(bn + rowS + 16 + lrow8) * K + gchunk;
    const unsigned short* bp3 = Bop + (size_t)(bn + rowS + 24 + lrow8) * K + gchunk;
    short* lA = As + rowS * 64;        // wave-uniform LDS bases
    short* lB = Bs + rowS * 64;

    for (int k0 = 0; k0 < K; k0 += 64) {
        GLDS16(ap0, lA);            GLDS16(ap1, lA + 8 * 64);
        GLDS16(ap2, lA + 16 * 64);  GLDS16(ap3, lA + 24 * 64);
        GLDS16(bp0, lB);            GLDS16(bp1, lB + 8 * 64);
        GLDS16(bp2, lB + 16 * 64);  GLDS16(bp3, lB + 24 * 64);
        ap0 += 64; ap1 += 64; ap2 += 64; ap3 += 64;
        bp0 += 64; bp1 += 64; bp2 += 64; bp3 += 64;
        __syncthreads();

        short8 a0[4], b0[4], a1[4], b1[4];
#pragma unroll
        for (int i = 0; i < 4; ++i) {
            a0[i] = *(const short8*)&As[(wm + i * 16 + r16) * 64 + pc0];
            b0[i] = *(const short8*)&Bs[(wn + i * 16 + r16) * 64 + pc0];
            a1[i] = *(const short8*)&As[(wm + i * 16 + r16) * 64 + pc1];
            b1[i] = *(const short8*)&Bs[(wn + i * 16 + r16) * 64 + pc1];
        }
#pragma unroll
        for (int i = 0; i < 4; ++i)
#pragma unroll
            for (int j = 0; j < 4; ++j) {
                acc[i][j] = __builtin_amdgcn_mfma_f32_16x16x32_bf16(a0[i], b0[j], acc[i][j], 0, 0, 0);
                acc[i][j] = __builtin_amdgcn_mfma_f32_16x16x32_bf16(a1[i], b1[j], acc[i][j], 0, 0, 0);
            }
        __syncthreads();
    }

    int col = lane & 15, rq = (lane >> 4) * 4;
#pragma unroll
    for (int i = 0; i < 4; ++i) {
#pragma unroll
        for (int r = 0; r < 4; ++r) {
            int m = bm + wm + i * 16 + rq + r;
#pragma unroll
            for (int j = 0; j < 4; ++j)
                C[(size_t)m * N + bn + wn + j * 16 + col] = acc[i][j][r];
        }
    }
}

// ---------------- 9-tap patch stencil: S[q][p] = invn[p] * sum_{u,v} C[q+δ][p+δ], δ=64du+dv ----------------
// XCD swizzle: blocks with equal (blk&7) share an XCD and own a contiguous 512-row q range.
__global__ __launch_bounds__(256) void stencil_norm_kernel(
    const float* __restrict__ C, const float* __restrict__ invn,
    float* __restrict__ Sout)
{
    int blk = blockIdx.x;
    int q = ((blk & 7) << 9) | (blk >> 3);
    int t = threadIdx.x;
    int qy = q >> 6, qx = q & 63;
    int px = t & 63;
    int py0 = t >> 6;
    float acc[16] = {};
#pragma unroll
    for (int du = -1; du <= 1; ++du) {
        if (qy + du < 0 || qy + du > 63) continue;
#pragma unroll
        for (int dv = -1; dv <= 1; ++dv) {
            if (qx + dv < 0 || qx + dv > 63) continue;
            if (px + dv < 0 || px + dv > 63) continue;
            const float* row = C + (size_t)(q + 64 * du + dv) * LTOT + 64 * du + dv;
#pragma unroll
            for (int i = 0; i < 16; ++i) {
                int py = py0 + 4 * i;
                if (py + du < 0 || py + du > 63) continue;
                acc[i] += row[t + 256 * i];
            }
        }
    }
    float* orow = Sout + (size_t)q * LTOT;
#pragma unroll
    for (int i = 0; i < 16; ++i)
        orow[t + 256 * i] = acc[i] * invn[t + 256 * i];
}

// ---------------- fused: (fuse2 o fuse1) 9-tap diagonal stencil + row softmax + bf16 write ----------------
__global__ __launch_bounds__(256) void fused_conv_softmax_kernel(
    const float* __restrict__ S, const float* __restrict__ mmv,
    unsigned short* __restrict__ S16)
{
    __shared__ float redmax[4];
    __shared__ float redsum[4];
    int blk = blockIdx.x;
    int q = ((blk & 7) << 9) | (blk >> 3);
    int t = threadIdx.x;
    int lane = t & 63, wid = t >> 6;

    int rbase = ((q & 63) << 6) | (q >> 6);     // swap(q)
    int rrs[3];
    bool rok[3];
#pragma unroll
    for (int j = 0; j < 3; ++j) {
        int r2 = rbase + (j - 1);
        rok[j] = (r2 >= 0) && (r2 < LTOT);
        rrs[j] = ((r2 & 63) << 6) | ((r2 >> 6) & 63);   // swap(r2)
    }

    float v[16], m[16];
#pragma unroll
    for (int i = 0; i < 16; ++i) {
        int c = t + (i << 8);                   // column p, 0..4095
        int cbase = ((c & 63) << 6) | (c >> 6); // swap(c)
        float s = 0.f;
#pragma unroll
        for (int j = 0; j < 3; ++j) {           // d2 = j-1 (fuse2 order)
            if (!rok[j]) continue;
            int c2 = cbase + (j - 1);
            if (c2 < 0 || c2 >= LTOT) continue;
            int cc = ((c2 & 63) << 6) | (c2 >> 6);  // swap(c2); interior: c + 64*d2
            int rr = rrs[j];
            float tsum = 0.f;
#pragma unroll
            for (int d1 = -1; d1 <= 1; ++d1) {  // fuse1 order
                int a = rr + d1, bcol = cc + d1;
                if (a >= 0 && a < LTOT && bcol >= 0 && bcol < LTOT)
                    tsum += S[(size_t)a * LTOT + bcol];
            }
            s += tsum;
        }
        float mmx = mmv[c];
        m[i] = mmx;
        v[i] = s * mmx * SCALE_F;
    }

    float mx = v[0];
#pragma unroll
    for (int i = 1; i < 16; ++i) mx = fmaxf(mx, v[i]);
#pragma unroll
    for (int o = 32; o; o >>= 1) mx = fmaxf(mx, __shfl_xor(mx, o));
    if (lane == 0) redmax[wid] = mx;
    __syncthreads();
    float gmx = fmaxf(fmaxf(redmax[0], redmax[1]), fmaxf(redmax[2], redmax[3]));

    float s = 0.f;
#pragma unroll
    for (int i = 0; i < 16; ++i) {
        v[i] = __expf(v[i] - gmx);
        s += v[i];
    }
#pragma unroll
    for (int o = 32; o; o >>= 1) s += __shfl_xor(s, o);
    if (lane == 0) redsum[wid] = s;
    __syncthreads();
    float inv = 1.f / (redsum[0] + redsum[1] + redsum[2] + redsum[3]);

    unsigned short* orow = S16 + (size_t)q * LTOT;
#pragma unroll
    for (int i = 0; i < 16; ++i)
        orow[t + (i << 8)] = f2bf(v[i] * inv * m[i]);
}

// ---------------- overlap-add of weighted 4x4 patches (stride 2), /4 ----------------
// C2t is TRANSPOSED: [m2][q] = [(c,kd,ke)][oy*64+ox] -> taps contiguous across threads (x->ox).
__global__ void output_kernel(const float* __restrict__ C2t, float* __restrict__ out) {
    int idx = blockIdx.x * blockDim.x + threadIdx.x;   // CC*HH*WW
    int x = idx & 127;
    int y = (idx >> 7) & 127;
    int c = idx >> 14;
    int oylo = max(0, (y - 1) >> 1), oyhi = min(63, (y + 1) >> 1);
    int oxlo = max(0, (x - 1) >> 1), oxhi = min(63, (x + 1) >> 1);
    float s = 0.f;
    for (int oy = oylo; oy <= oyhi; ++oy)
        for (int ox = oxlo; ox <= oxhi; ++ox) {
            int kd = y - 2 * oy + 1;
            int ke = x - 2 * ox + 1;
            s += C2t[(size_t)(c * 16 + kd * 4 + ke) * LTOT + oy * 64 + ox];
        }
    out[idx] = s * 0.25f;
}

extern "C" void kernel_launch(void* const* d_in, const int* in_sizes, int n_in,
                              void* d_out, int out_size, void* d_ws, size_t ws_size,
                              hipStream_t stream) {
    (void)in_sizes; (void)n_in; (void)out_size; (void)ws_size;
    const float* f    = (const float*)d_in[0];
    const float* b    = (const float*)d_in[1];
    const float* mask = (const float*)d_in[2];
    float* out = (float*)d_out;

    const size_t SZ_MAT = (size_t)LTOT * LTOT * 4;   // 64 MB
    const size_t SZ_WR  = (size_t)K2 * LTOT * 2;     // 16 MB
    const size_t SZ_SP  = (size_t)LTOT * K0S * 2;    // 3 MB
    const size_t SZ_V   = (size_t)LTOT * 4;

    auto pad = [](size_t n) { return (n + 255) & ~(size_t)255; };
    char* p = (char*)d_ws;
    auto take = [&](size_t n) -> void* { void* r = (void*)p; p += pad(n); return r; };

    // footprint: 64 + 64 + 16 + 16 + 4*3 + small ~= 172 MB (proven-safe)
    float* Buf1 = (float*)take(SZ_MAT);   // Cpix -> S16 (lower 32 MB)
    float* Buf2 = (float*)take(SZ_MAT);   // Sp   -> C2t (lower 32 MB)
    unsigned short* W0 = (unsigned short*)take(SZ_WR);
    unsigned short* W1 = (unsigned short*)take(SZ_WR);
    unsigned short* Bsp0 = (unsigned short*)take(SZ_SP);
    unsigned short* Fsp0 = (unsigned short*)take(SZ_SP);
    unsigned short* Bsp1 = (unsigned short*)take(SZ_SP);
    unsigned short* Fsp1 = (unsigned short*)take(SZ_SP);
    float* ssq0 = (float*)take(SZ_V);  float* ssq1 = (float*)take(SZ_V);
    float* invn0 = (float*)take(SZ_V); float* invn1 = (float*)take(SZ_V);
    float* mmv0 = (float*)take(SZ_V);  float* mmv1 = (float*)take(SZ_V);

    const float* f0 = f,  *b0 = b;
    const float* f1 = f + IMG, *b1 = b + IMG;

    unsigned short* S16 = (unsigned short*)Buf1;   // 32 MB, after Cpix dead
    float* C2t = Buf2;                              // 32 MB, after Sp dead

    // ---- merged prep (both batches); ssq fused into the b split passes ----
    Prep4 P{{b0, f0, b1, f1}, {Bsp0, Fsp0, Bsp1, Fsp1},
            {ssq0, nullptr, ssq1, nullptr}, {1, 0, 1, 0}};
    split_ds_kernel<<<dim3(LTOT, 1, 4), 128, 0, stream>>>(P);
    PtrN2 nm{{ssq0, ssq1}, {invn0, invn1}, {mmv0, mmv1}};
    norm_mm_kernel<<<dim3(16, 1, 2), 256, 0, stream>>>(nm, mask);
    PtrR2 rw{{b0, b1}, {W0, W1}};
    im2col_rawt_kernel<<<dim3((size_t)K2 * LTOT / 256, 1, 2), 256, 0, stream>>>(rw);

    // ---- per-batch pipeline ----
    for (int bi = 0; bi < 2; ++bi) {
        const unsigned short* Fsp = bi ? Fsp1 : Fsp0;
        const unsigned short* Bsp = bi ? Bsp1 : Bsp0;
        const unsigned short* W   = bi ? W1 : W0;
        const float* invn = bi ? invn1 : invn0;
        const float* mmv  = bi ? mmv1 : mmv0;

        // Cpix[q][p] = sum_c fd[c][q]*bd[c][p]   (split-concat fp32-accurate, K=384)
        gemm_mfma<<<dim3(32, 32), 256, 0, stream>>>(Fsp, Bsp, Buf1, LTOT, LTOT, K0S);

        // patch inner products: 9-tap diagonal stencil + invn column scale
        stencil_norm_kernel<<<LTOT, 256, 0, stream>>>(Buf1, invn, Buf2);

        // fused (fuse2 o fuse1) + softmax + bf16 cast  (Cpix dead -> S16 in Buf1 lower half)
        fused_conv_softmax_kernel<<<LTOT, 256, 0, stream>>>(Buf2, mmv, S16);

        // TRANSPOSED GEMM2: C2t[m2][q] = sum_p W[m2][p] * S16[q][p]   (Sp dead -> C2t in Buf2)
        gemm_mfma<<<dim3(LTOT / 128, K2 / 128), 256, 0, stream>>>(W, S16, C2t, K2, LTOT, LTOT);

        output_kernel<<<CC * HH * WW / 256, 256, 0, stream>>>(C2t, out + (size_t)bi * IMG);
    }
}

// Round 12
// 597.575 us; speedup vs baseline: 1.2541x; 1.0003x over previous
//
#include <hip/hip_runtime.h>

#define CC 128
#define HH 128
#define WW 128
#define DH 64
#define DW 64
#define LTOT 4096          // DH*DW patches / fg positions
#define K0S 384            // 3*128 split-concat K for the pixel-pair GEMM
#define K2 2048            // CC*4*4
#define SCALE_F 10.0f
#define IMG ((size_t)CC * HH * WW)

typedef __attribute__((ext_vector_type(8))) short short8;
typedef __attribute__((ext_vector_type(4))) float f32x4;

// ---- pointer-pack structs (batch-merged prep via blockIdx.z) ----
struct Prep4 { const float* src[4]; unsigned short* dst[4]; float* ssq[4]; int lo[4]; };
struct PtrN2 { const float* ssq[2]; float* invn[2]; float* mmv[2]; };
struct PtrR2 { const float* src[2]; unsigned short* dst[2]; };

// ---- bf16 helpers (RNE) ----
__device__ __forceinline__ unsigned short f2bf(float x) {
    union { float f; unsigned u; } v; v.f = x;
    unsigned r = v.u + 0x7fffu + ((v.u >> 16) & 1u);
    return (unsigned short)(r >> 16);
}
__device__ __forceinline__ float bf2f(unsigned short b) {
    union { unsigned u; float f; } v; v.u = ((unsigned)b) << 16;
    return v.f;
}

#define GLDS16(g, l) __builtin_amdgcn_global_load_lds( \
    (const __attribute__((address_space(1))) void*)(g), \
    (__attribute__((address_space(3))) void*)(l), 16, 0, 0)

// ---------------- downsample (::2) + fp32->bf16 split + (for b) fused ssq reduce ----------------
// b gets [hi, lo, hi], f gets [hi, hi, lo]  =>  products sum to hi*hi + lo*hi + hi*lo
__global__ __launch_bounds__(128) void split_ds_kernel(Prep4 P) {
    __shared__ float partial[2];
    int z = blockIdx.z;
    const float* __restrict__ src = P.src[z];
    unsigned short* __restrict__ dst = P.dst[z];
    int lo_in_seg1 = P.lo[z];
    int n = blockIdx.x;          // 4096 pixels
    int c = threadIdx.x;         // 128 channels
    int ny = n >> 6, nx = n & 63;
    float v = src[((size_t)c * HH + 2 * ny) * WW + 2 * nx];
    unsigned short hi = f2bf(v);
    unsigned short lo = f2bf(v - bf2f(hi));
    unsigned short* drow = dst + (size_t)n * K0S;
    drow[c]       = hi;
    drow[128 + c] = lo_in_seg1 ? lo : hi;
    drow[256 + c] = lo_in_seg1 ? hi : lo;

    float* ssq = P.ssq[z];
    if (ssq) {                   // b images only: per-pixel channel sum of squares
        float s2 = v * v;
#pragma unroll
        for (int o = 32; o; o >>= 1) s2 += __shfl_xor(s2, o);
        if ((threadIdx.x & 63) == 0) partial[threadIdx.x >> 6] = s2;
        __syncthreads();
        if (threadIdx.x == 0) ssq[n] = partial[0] + partial[1];
    }
}

// ---------------- raw 4x4 stride-2 patches of full-res b, transposed: dst[m2][p] bf16 ----------------
__global__ __launch_bounds__(256) void im2col_rawt_kernel(PtrR2 P) {
    int z = blockIdx.z;
    const float* __restrict__ src = P.src[z];
    unsigned short* __restrict__ dst = P.dst[z];
    int idx = blockIdx.x * 256 + threadIdx.x;   // K2*LTOT threads, p fastest
    int p = idx & (LTOT - 1);
    int m = idx >> 12;
    int px = p & 63, py = p >> 6;
    int ke = m & 3, kd = (m >> 2) & 3, c = m >> 4;
    int yy = 2 * py - 1 + kd, xx = 2 * px - 1 + ke;
    float v = 0.f;
    if (yy >= 0 && yy < HH && xx >= 0 && xx < WW)
        v = src[((size_t)c * HH + yy) * WW + xx];
    dst[idx] = f2bf(v);
}

// ---------------- patch inverse norm + mask gate ----------------
__global__ void norm_mm_kernel(PtrN2 P, const float* __restrict__ mask) {
    int z = blockIdx.z;
    const float* __restrict__ ssq = P.ssq[z];
    float* __restrict__ inv_norm = P.invn[z];
    float* __restrict__ mmv = P.mmv[z];
    int p = blockIdx.x * blockDim.x + threadIdx.x;     // 4096
    int px = p & 63, py = p >> 6;
    float s = 0.f, ms = 0.f;
    for (int di = -1; di <= 1; ++di)
        for (int dj = -1; dj <= 1; ++dj) {
            int y = py + di, x = px + dj;
            if (y >= 0 && y < DH && x >= 0 && x < DW) {
                s += ssq[y * 64 + x];
                ms += mask[(size_t)(2 * y) * WW + 2 * x];
            }
        }
    float n = sqrtf(s);
    if (n < 1e-4f) n = 1e-4f;
    inv_norm[p] = 1.f / n;
    mmv[p] = (ms == 0.f) ? 1.f : 0.f;
}

// ---------------- bf16 MFMA GEMM, BK=64, hoisted running pointers, XOR swizzle ----------------
// A[M][K], B[N][K], C[M][N] fp32. 128x128 tile, 4 waves 2x2, each 4x4x(2 k-slab) MFMA 16x16x32.
// LDS rows of 128B = 8 chunks of 16B; chunk slot s of row m holds global chunk s ^ (m&7).
__global__ __launch_bounds__(256) void gemm_mfma(
    const unsigned short* __restrict__ Aop, const unsigned short* __restrict__ Bop,
    float* __restrict__ C, int M, int N, int K)
{
    __shared__ short As[128 * 64];
    __shared__ short Bs[128 * 64];
    int tid = threadIdx.x;
    int wave = tid >> 6, lane = tid & 63;
    int wm = (wave >> 1) * 64;
    int wn = (wave & 1) * 64;
    int bm = blockIdx.y * 128, bn = blockIdx.x * 128;

    int rowS = wave * 32;              // wave stages rows [rowS, rowS+32)
    int lrow8 = lane >> 3;             // 0..7 (row within 8-row staging group)
    int gchunk = ((lane & 7) ^ lrow8) * 8;   // swizzled global k-offset (shorts)

    f32x4 acc[4][4] = {};

    int quad = lane >> 4;              // 0..3
    int r16 = lane & 15;
    int pc0 = ((quad)     ^ (r16 & 7)) * 8;  // physical chunk of k-slab 0
    int pc1 = ((4 + quad) ^ (r16 & 7)) * 8;  // physical chunk of k-slab 1

    // hoisted running pointers (k0-invariant base; += 64 shorts per iter)
    const unsigned short* ap0 = Aop + (size_t)(bm + rowS +  0 + lrow8) * K + gchunk;
    const unsigned short* ap1 = Aop + (size_t)(bm + rowS +  8 + lrow8) * K + gchunk;
    const unsigned short* ap2 = Aop + (size_t)(bm + rowS + 16 + lrow8) * K + gchunk;
    const unsigned short* ap3 = Aop + (size_t)(bm + rowS + 24 + lrow8) * K + gchunk;
    const unsigned short* bp0 = Bop + (size_t)(bn + rowS +  0 + lrow8) * K + gchunk;
    const unsigned short* bp1 = Bop + (size_t)(bn + rowS +  8 + lrow8) * K + gchunk;
    const unsigned short* bp2 = Bop + (size_t)(bn + rowS + 16 + lrow8) * K + gchunk;
    const unsigned short* bp3 = Bop + (size_t)(bn + rowS + 24 + lrow8) * K + gchunk;
    short* lA = As + rowS * 64;        // wave-uniform LDS bases
    short* lB = Bs + rowS * 64;

    for (int k0 = 0; k0 < K; k0 += 64) {
        GLDS16(ap0, lA);            GLDS16(ap1, lA + 8 * 64);
        GLDS16(ap2, lA + 16 * 64);  GLDS16(ap3, lA + 24 * 64);
        GLDS16(bp0, lB);            GLDS16(bp1, lB + 8 * 64);
        GLDS16(bp2, lB + 16 * 64);  GLDS16(bp3, lB + 24 * 64);
        ap0 += 64; ap1 += 64; ap2 += 64; ap3 += 64;
        bp0 += 64; bp1 += 64; bp2 += 64; bp3 += 64;
        __syncthreads();

        short8 a0[4], b0[4], a1[4], b1[4];
#pragma unroll
        for (int i = 0; i < 4; ++i) {
            a0[i] = *(const short8*)&As[(wm + i * 16 + r16) * 64 + pc0];
            b0[i] = *(const short8*)&Bs[(wn + i * 16 + r16) * 64 + pc0];
            a1[i] = *(const short8*)&As[(wm + i * 16 + r16) * 64 + pc1];
            b1[i] = *(const short8*)&Bs[(wn + i * 16 + r16) * 64 + pc1];
        }
#pragma unroll
        for (int i = 0; i < 4; ++i)
#pragma unroll
            for (int j = 0; j < 4; ++j) {
                acc[i][j] = __builtin_amdgcn_mfma_f32_16x16x32_bf16(a0[i], b0[j], acc[i][j], 0, 0, 0);
                acc[i][j] = __builtin_amdgcn_mfma_f32_16x16x32_bf16(a1[i], b1[j], acc[i][j], 0, 0, 0);
            }
        __syncthreads();
    }

    int col = lane & 15, rq = (lane >> 4) * 4;
#pragma unroll
    for (int i = 0; i < 4; ++i) {
#pragma unroll
        for (int r = 0; r < 4; ++r) {
            int m = bm + wm + i * 16 + rq + r;
#pragma unroll
            for (int j = 0; j < 4; ++j)
                C[(size_t)m * N + bn + wn + j * 16 + col] = acc[i][j][r];
        }
    }
}

// ---------------- 9-tap patch stencil: S[q][p] = invn[p] * sum_{u,v} C[q+δ][p+δ], δ=64du+dv ----------------
// XCD swizzle: blocks with equal (blk&7) share an XCD and own a contiguous 512-row q range.
__global__ __launch_bounds__(256) void stencil_norm_kernel(
    const float* __restrict__ C, const float* __restrict__ invn,
    float* __restrict__ Sout)
{
    int blk = blockIdx.x;
    int q = ((blk & 7) << 9) | (blk >> 3);
    int t = threadIdx.x;
    int qy = q >> 6, qx = q & 63;
    int px = t & 63;
    int py0 = t >> 6;
    float acc[16] = {};
#pragma unroll
    for (int du = -1; du <= 1; ++du) {
        if (qy + du < 0 || qy + du > 63) continue;
#pragma unroll
        for (int dv = -1; dv <= 1; ++dv) {
            if (qx + dv < 0 || qx + dv > 63) continue;
            if (px + dv < 0 || px + dv > 63) continue;
            const float* row = C + (size_t)(q + 64 * du + dv) * LTOT + 64 * du + dv;
#pragma unroll
            for (int i = 0; i < 16; ++i) {
                int py = py0 + 4 * i;
                if (py + du < 0 || py + du > 63) continue;
                acc[i] += row[t + 256 * i];
            }
        }
    }
    float* orow = Sout + (size_t)q * LTOT;
#pragma unroll
    for (int i = 0; i < 16; ++i)
        orow[t + 256 * i] = acc[i] * invn[t + 256 * i];
}

// ---------------- fused: (fuse2 o fuse1) 9-tap diagonal stencil + row softmax + bf16 write ----------------
// __launch_bounds__(256, 4): grant 128-VGPR budget so v[16]+m[16] stay LIVE across the
// softmax barriers. Default compilation picked 24 VGPRs (8 waves/SIMD) and rematerialized
// the whole stencil (re-reading S from L2) in each of the max/sum/write passes — R11 PMC
// showed VGPR=24, occupancy 81%, no spill traffic, 91.5 µs.
__global__ __launch_bounds__(256, 4) void fused_conv_softmax_kernel(
    const float* __restrict__ S, const float* __restrict__ mmv,
    unsigned short* __restrict__ S16)
{
    __shared__ float redmax[4];
    __shared__ float redsum[4];
    int blk = blockIdx.x;
    int q = ((blk & 7) << 9) | (blk >> 3);
    int t = threadIdx.x;
    int lane = t & 63, wid = t >> 6;

    int rbase = ((q & 63) << 6) | (q >> 6);     // swap(q)
    int rrs[3];
    bool rok[3];
#pragma unroll
    for (int j = 0; j < 3; ++j) {
        int r2 = rbase + (j - 1);
        rok[j] = (r2 >= 0) && (r2 < LTOT);
        rrs[j] = ((r2 & 63) << 6) | ((r2 >> 6) & 63);   // swap(r2)
    }

    float v[16], m[16];
#pragma unroll
    for (int i = 0; i < 16; ++i) {
        int c = t + (i << 8);                   // column p, 0..4095
        int cbase = ((c & 63) << 6) | (c >> 6); // swap(c)
        float s = 0.f;
#pragma unroll
        for (int j = 0; j < 3; ++j) {           // d2 = j-1 (fuse2 order)
            if (!rok[j]) continue;
            int c2 = cbase + (j - 1);
            if (c2 < 0 || c2 >= LTOT) continue;
            int cc = ((c2 & 63) << 6) | (c2 >> 6);  // swap(c2); interior: c + 64*d2
            int rr = rrs[j];
            float tsum = 0.f;
#pragma unroll
            for (int d1 = -1; d1 <= 1; ++d1) {  // fuse1 order
                int a = rr + d1, bcol = cc + d1;
                if (a >= 0 && a < LTOT && bcol >= 0 && bcol < LTOT)
                    tsum += S[(size_t)a * LTOT + bcol];
            }
            s += tsum;
        }
        float mmx = mmv[c];
        m[i] = mmx;
        v[i] = s * mmx * SCALE_F;
    }

    float mx = v[0];
#pragma unroll
    for (int i = 1; i < 16; ++i) mx = fmaxf(mx, v[i]);
#pragma unroll
    for (int o = 32; o; o >>= 1) mx = fmaxf(mx, __shfl_xor(mx, o));
    if (lane == 0) redmax[wid] = mx;
    __syncthreads();
    float gmx = fmaxf(fmaxf(redmax[0], redmax[1]), fmaxf(redmax[2], redmax[3]));

    float s = 0.f;
#pragma unroll
    for (int i = 0; i < 16; ++i) {
        v[i] = __expf(v[i] - gmx);
        s += v[i];
    }
#pragma unroll
    for (int o = 32; o; o >>= 1) s += __shfl_xor(s, o);
    if (lane == 0) redsum[wid] = s;
    __syncthreads();
    float inv = 1.f / (redsum[0] + redsum[1] + redsum[2] + redsum[3]);

    unsigned short* orow = S16 + (size_t)q * LTOT;
#pragma unroll
    for (int i = 0; i < 16; ++i)
        orow[t + (i << 8)] = f2bf(v[i] * inv * m[i]);
}

// ---------------- overlap-add of weighted 4x4 patches (stride 2), /4 ----------------
// C2t is TRANSPOSED: [m2][q] = [(c,kd,ke)][oy*64+ox] -> taps contiguous across threads (x->ox).
__global__ void output_kernel(const float* __restrict__ C2t, float* __restrict__ out) {
    int idx = blockIdx.x * blockDim.x + threadIdx.x;   // CC*HH*WW
    int x = idx & 127;
    int y = (idx >> 7) & 127;
    int c = idx >> 14;
    int oylo = max(0, (y - 1) >> 1), oyhi = min(63, (y + 1) >> 1);
    int oxlo = max(0, (x - 1) >> 1), oxhi = min(63, (x + 1) >> 1);
    float s = 0.f;
    for (int oy = oylo; oy <= oyhi; ++oy)
        for (int ox = oxlo; ox <= oxhi; ++ox) {
            int kd = y - 2 * oy + 1;
            int ke = x - 2 * ox + 1;
            s += C2t[(size_t)(c * 16 + kd * 4 + ke) * LTOT + oy * 64 + ox];
        }
    out[idx] = s * 0.25f;
}

extern "C" void kernel_launch(void* const* d_in, const int* in_sizes, int n_in,
                              void* d_out, int out_size, void* d_ws, size_t ws_size,
                              hipStream_t stream) {
    (void)in_sizes; (void)n_in; (void)out_size; (void)ws_size;
    const float* f    = (const float*)d_in[0];
    const float* b    = (const float*)d_in[1];
    const float* mask = (const float*)d_in[2];
    float* out = (float*)d_out;

    const size_t SZ_MAT = (size_t)LTOT * LTOT * 4;   // 64 MB
    const size_t SZ_WR  = (size_t)K2 * LTOT * 2;     // 16 MB
    const size_t SZ_SP  = (size_t)LTOT * K0S * 2;    // 3 MB
    const size_t SZ_V   = (size_t)LTOT * 4;

    auto pad = [](size_t n) { return (n + 255) & ~(size_t)255; };
    char* p = (char*)d_ws;
    auto take = [&](size_t n) -> void* { void* r = (void*)p; p += pad(n); return r; };

    // footprint: 64 + 64 + 16 + 16 + 4*3 + small ~= 172 MB (proven-safe)
    float* Buf1 = (float*)take(SZ_MAT);   // Cpix -> S16 (lower 32 MB)
    float* Buf2 = (float*)take(SZ_MAT);   // Sp   -> C2t (lower 32 MB)
    unsigned short* W0 = (unsigned short*)take(SZ_WR);
    unsigned short* W1 = (unsigned short*)take(SZ_WR);
    unsigned short* Bsp0 = (unsigned short*)take(SZ_SP);
    unsigned short* Fsp0 = (unsigned short*)take(SZ_SP);
    unsigned short* Bsp1 = (unsigned short*)take(SZ_SP);
    unsigned short* Fsp1 = (unsigned short*)take(SZ_SP);
    float* ssq0 = (float*)take(SZ_V);  float* ssq1 = (float*)take(SZ_V);
    float* invn0 = (float*)take(SZ_V); float* invn1 = (float*)take(SZ_V);
    float* mmv0 = (float*)take(SZ_V);  float* mmv1 = (float*)take(SZ_V);

    const float* f0 = f,  *b0 = b;
    const float* f1 = f + IMG, *b1 = b + IMG;

    unsigned short* S16 = (unsigned short*)Buf1;   // 32 MB, after Cpix dead
    float* C2t = Buf2;                              // 32 MB, after Sp dead

    // ---- merged prep (both batches); ssq fused into the b split passes ----
    Prep4 P{{b0, f0, b1, f1}, {Bsp0, Fsp0, Bsp1, Fsp1},
            {ssq0, nullptr, ssq1, nullptr}, {1, 0, 1, 0}};
    split_ds_kernel<<<dim3(LTOT, 1, 4), 128, 0, stream>>>(P);
    PtrN2 nm{{ssq0, ssq1}, {invn0, invn1}, {mmv0, mmv1}};
    norm_mm_kernel<<<dim3(16, 1, 2), 256, 0, stream>>>(nm, mask);
    PtrR2 rw{{b0, b1}, {W0, W1}};
    im2col_rawt_kernel<<<dim3((size_t)K2 * LTOT / 256, 1, 2), 256, 0, stream>>>(rw);

    // ---- per-batch pipeline ----
    for (int bi = 0; bi < 2; ++bi) {
        const unsigned short* Fsp = bi ? Fsp1 : Fsp0;
        const unsigned short* Bsp = bi ? Bsp1 : Bsp0;
        const unsigned short* W   = bi ? W1 : W0;
        const float* invn = bi ? invn1 : invn0;
        const float* mmv  = bi ? mmv1 : mmv0;

        // Cpix[q][p] = sum_c fd[c][q]*bd[c][p]   (split-concat fp32-accurate, K=384)
        gemm_mfma<<<dim3(32, 32), 256, 0, stream>>>(Fsp, Bsp, Buf1, LTOT, LTOT, K0S);

        // patch inner products: 9-tap diagonal stencil + invn column scale
        stencil_norm_kernel<<<LTOT, 256, 0, stream>>>(Buf1, invn, Buf2);

        // fused (fuse2 o fuse1) + softmax + bf16 cast  (Cpix dead -> S16 in Buf1 lower half)
        fused_conv_softmax_kernel<<<LTOT, 256, 0, stream>>>(Buf2, mmv, S16);

        // TRANSPOSED GEMM2: C2t[m2][q] = sum_p W[m2][p] * S16[q][p]   (Sp dead -> C2t in Buf2)
        gemm_mfma<<<dim3(LTOT / 128, K2 / 128), 256, 0, stream>>>(W, S16, C2t, K2, LTOT, LTOT);

        output_kernel<<<CC * HH * WW / 256, 256, 0, stream>>>(C2t, out + (size_t)bi * IMG);
    }
}